// Round 1
// baseline (656.133 us; speedup 1.0000x reference)
//
#include <hip/hip_runtime.h>
#include <math.h>

// Problem constants
#define NB   1024
#define NC   64
#define DIN  256
#define DH   128
#define DCP  32
#define NV   36

// Output flat offsets (fp32 elements), in reference return order:
// votes (1024,64,36,3,3)=21233664 | scale (.,36)=2359296 | pres_per_vote=2359296
// | pres_logit_per_caps=65536 | pres_logit_per_vote=2359296 | l2 scalar=1
// | raw (.,32)=2097152 | features=16777216  -> total 47251457
#define OFF0 0
#define OFF1 21233664
#define OFF2 23592960
#define OFF3 25952256
#define OFF4 26017792
#define OFF5 28377088
#define OFF6 28377089
#define OFF7 30474241

// LDS layout (float indices). Regions are phase-unioned; barriers separate uses.
#define SM_FST  0        // [128][33]  HsT (phase B input) then FsT (D2/D4 input)
#define SM_M    4224     // [32][6]    ccr matrices (rows 0,1 only; row2=0,0,1)
#define SM_PSIG 4416     // [32]       sigmoid(pres_logit_per_caps)
#define SM_CPS  4448     // [32][34]   caps_params (raw|1)
#define SM_XS   5536     // A: [32][33] X chunk
#define SM_W1C  6592     // A: [32][128] W1 chunk
#define SM_W2S  5536     // B: [128][32]
#define SM_WM   5536     // C: [33][128]
#define SM_WH   5536     // D2: [32][80] head-weight chunk
#define SM_HD   8096     // D2: [32][80] head logits
#define SM_HB   10656    // D2: [80] head biases
#define SM_WD   5536     // D4: [16][216] cpr weight chunk
#define SM_DYN  8992     // D4: [32][216] cpr_dynamic
#define SM_TOT  15904    // 63616 bytes

__device__ __forceinline__ float sigm(float x) { return 1.0f / (1.0f + __expf(-x)); }
__device__ __forceinline__ float tanh5(float x) {
    // tanh(5x), clamped so exp never overflows (tanh(+-15)==+-1 in fp32)
    x = fminf(fmaxf(5.0f * x, -15.0f), 15.0f);
    float z = __expf(2.0f * x);
    return (z - 1.0f) / (z + 1.0f);
}
// geometric_transform: pose[6] -> first two rows of the 3x3 matrix (row2 = 0,0,1)
__device__ __forceinline__ void geo(const float* p, float* m) {
    float sx = sigm(p[0]) + 0.01f;
    float sy = sigm(p[1]) + 0.01f;
    float th = p[2] * 6.28318530717958647692f;
    float sh = tanh5(p[3]);
    float tx = tanh5(p[4]);
    float ty = tanh5(p[5]);
    float cc = __cosf(th), ss = __sinf(th);
    m[0] =  sx * cc + sh * sy * ss;
    m[1] = -sx * ss + sh * sy * cc;
    m[2] = tx;
    m[3] = sy * ss;
    m[4] = sy * cc;
    m[5] = ty;
}

__global__ void zero_l2_kernel(float* out) { out[OFF5] = 0.0f; }

__global__ __launch_bounds__(256)
void caps_fused_kernel(const float* __restrict__ feat,
                       const float* __restrict__ w1,  const float* __restrict__ b1,
                       const float* __restrict__ w2,  const float* __restrict__ b2,
                       const float* __restrict__ wm,  const float* __restrict__ bm,
                       const float* __restrict__ wdy,
                       const float* __restrict__ wccr,const float* __restrict__ bccr,
                       const float* __restrict__ wpc, const float* __restrict__ bpc,
                       const float* __restrict__ wpv, const float* __restrict__ bpv,
                       const float* __restrict__ wsv, const float* __restrict__ bsv,
                       const float* __restrict__ cst,
                       float* __restrict__ out)
{
    __shared__ float sm[SM_TOT];
    const int t  = threadIdx.x;
    const int c  = blockIdx.y;          // capsule
    const int rb = blockIdx.x * 32;     // batch-tile base

    // ============ Phase A: HsT = relu(X @ W1 + b1)^T, 32x128, K=256 ============
    {
        const int tx = t & 31;          // col group: cols tx*4..+3
        const int ty = t >> 5;          // 8 groups of 4 rows
        float acc[4][4] = {};
        const int xrow = t >> 3, xk4 = (t & 7) << 2;
        for (int k0 = 0; k0 < DIN; k0 += 32) {
            __syncthreads();
            {   // stage X chunk [32 rows][32 k] + features passthrough (output 7)
                const int gi = (rb + xrow) * (NC * DIN) + c * DIN + k0 + xk4;
                const float4 v = *(const float4*)&feat[gi];
                float* xs = &sm[SM_XS + xrow * 33 + xk4];
                xs[0] = v.x; xs[1] = v.y; xs[2] = v.z; xs[3] = v.w;
                float* o7 = &out[OFF7 + gi];   // off7 is odd -> scalar stores
                o7[0] = v.x; o7[1] = v.y; o7[2] = v.z; o7[3] = v.w;
            }
#pragma unroll
            for (int p = 0; p < 4; ++p) {  // stage W1 chunk [32][128]
                const int idx = t + p * 256;
                *(float4*)&sm[SM_W1C + idx * 4] =
                    *(const float4*)&w1[c * (DIN * DH) + k0 * DH + idx * 4];
            }
            __syncthreads();
#pragma unroll 8
            for (int kk = 0; kk < 32; ++kk) {
                const float a0 = sm[SM_XS + (ty * 4 + 0) * 33 + kk];
                const float a1 = sm[SM_XS + (ty * 4 + 1) * 33 + kk];
                const float a2 = sm[SM_XS + (ty * 4 + 2) * 33 + kk];
                const float a3 = sm[SM_XS + (ty * 4 + 3) * 33 + kk];
                const float4 bv = *(const float4*)&sm[SM_W1C + kk * DH + tx * 4];
                acc[0][0] += a0 * bv.x; acc[0][1] += a0 * bv.y; acc[0][2] += a0 * bv.z; acc[0][3] += a0 * bv.w;
                acc[1][0] += a1 * bv.x; acc[1][1] += a1 * bv.y; acc[1][2] += a1 * bv.z; acc[1][3] += a1 * bv.w;
                acc[2][0] += a2 * bv.x; acc[2][1] += a2 * bv.y; acc[2][2] += a2 * bv.z; acc[2][3] += a2 * bv.w;
                acc[3][0] += a3 * bv.x; acc[3][1] += a3 * bv.y; acc[3][2] += a3 * bv.z; acc[3][3] += a3 * bv.w;
            }
        }
        const float4 bb4 = *(const float4*)&b1[c * DH + tx * 4];
        const float bb[4] = { bb4.x, bb4.y, bb4.z, bb4.w };
#pragma unroll
        for (int i = 0; i < 4; ++i)
#pragma unroll
            for (int j = 0; j < 4; ++j) {
                float v = fmaxf(acc[i][j] + bb[j], 0.0f);
                sm[SM_FST + (tx * 4 + j) * 33 + (ty * 4 + i)] = v;  // transposed
            }
    }
    __syncthreads();

    // ============ Phase B: raw = relu(H @ W2 + b2), 32x32, K=128 ============
#pragma unroll
    for (int p = 0; p < 4; ++p) {
        const int idx = t + p * 256;
        *(float4*)&sm[SM_W2S + idx * 4] = *(const float4*)&w2[c * (DH * DCP) + idx * 4];
    }
    __syncthreads();
    {
        const int b = t & 31;
        const int j4 = (t >> 5) << 2;
        float acc[4] = {};
#pragma unroll 8
        for (int k = 0; k < DH; ++k) {
            const float h = sm[SM_FST + k * 33 + b];
            const float4 wv = *(const float4*)&sm[SM_W2S + k * DCP + j4];
            acc[0] += h * wv.x; acc[1] += h * wv.y; acc[2] += h * wv.z; acc[3] += h * wv.w;
        }
#pragma unroll
        for (int jj = 0; jj < 4; ++jj) {
            const float v = fmaxf(acc[jj] + b2[c * DCP + j4 + jj], 0.0f);
            out[OFF6 + ((rb + b) * NC + c) * DCP + j4 + jj] = v;   // output 6
            sm[SM_CPS + b * 34 + j4 + jj] = v;
        }
        if (t < 32) sm[SM_CPS + t * 34 + 32] = 1.0f;               // caps_exist
    }
    __syncthreads();

    // ============ Phase C: caps_feat = relu(CP @ Wm + bm), 32x128, K=33 ============
#pragma unroll
    for (int p = 0; p < 5; ++p) {
        const int idx = t + p * 256;
        if (idx < 1056)
            *(float4*)&sm[SM_WM + idx * 4] = *(const float4*)&wm[c * (33 * DH) + idx * 4];
    }
    __syncthreads();
    {
        const int b = t & 31;
        const int nb = (t >> 5) << 4;   // 16 cols per thread
        float acc[16] = {};
        for (int k = 0; k < 33; ++k) {
            const float a = sm[SM_CPS + b * 34 + k];
#pragma unroll
            for (int jq = 0; jq < 4; ++jq) {
                const float4 wv = *(const float4*)&sm[SM_WM + k * DH + nb + jq * 4];
                acc[jq*4+0] += a * wv.x; acc[jq*4+1] += a * wv.y;
                acc[jq*4+2] += a * wv.z; acc[jq*4+3] += a * wv.w;
            }
        }
#pragma unroll
        for (int j = 0; j < 16; ++j) {
            const float v = fmaxf(acc[j] + bm[c * DH + nb + j], 0.0f);
            sm[SM_FST + (nb + j) * 33 + b] = v;  // FsT overwrites HsT (B is done)
        }
    }
    __syncthreads();

    // ============ Phase D2: heads [ccr|pres_caps|pres_vote|scale_vote] 32x80, K=128 ============
    if (t < 80) {   // stage per-col bias
        float v = 0.0f;
        if (t < 6)       v = bccr[c * 6 + t];
        else if (t == 6) v = bpc[c];
        else if (t < 43) v = bpv[c * NV + (t - 7)];
        else if (t < 79) v = bsv[c * NV + (t - 43)];
        sm[SM_HB + t] = v;
    }
    {
        const int txx = t & 15;   // cols txx*5..+4
        const int tyy = t >> 4;   // rows tyy*2, tyy*2+1
        float acc[2][5] = {};
        for (int k0 = 0; k0 < DH; k0 += 32) {
            __syncthreads();
#pragma unroll
            for (int p = 0; p < 10; ++p) {   // stage head-weight chunk [32][80]
                const int idx = t + p * 256;
                const int kk = idx / 80, col = idx % 80;
                const int kg = k0 + kk;
                float v = 0.0f;
                if (col < 6)        v = wccr[c * (DH * 6) + kg * 6 + col];
                else if (col == 6)  v = wpc[c * DH + kg];
                else if (col < 43)  v = wpv[c * (DH * NV) + kg * NV + (col - 7)];
                else if (col < 79)  v = wsv[c * (DH * NV) + kg * NV + (col - 43)];
                sm[SM_WH + kk * 80 + col] = v;
            }
            __syncthreads();
#pragma unroll 4
            for (int kk = 0; kk < 32; ++kk) {
                const float a0 = sm[SM_FST + (k0 + kk) * 33 + tyy * 2 + 0];
                const float a1 = sm[SM_FST + (k0 + kk) * 33 + tyy * 2 + 1];
#pragma unroll
                for (int j = 0; j < 5; ++j) {
                    const float w = sm[SM_WH + kk * 80 + txx * 5 + j];
                    acc[0][j] += a0 * w;
                    acc[1][j] += a1 * w;
                }
            }
        }
#pragma unroll
        for (int i = 0; i < 2; ++i)
#pragma unroll
            for (int j = 0; j < 5; ++j)
                sm[SM_HD + (tyy * 2 + i) * 80 + txx * 5 + j] = acc[i][j];
    }
    __syncthreads();

    // D2b: per-row ccr matrix + pres_caps sigmoid (wave 0 only)
    if (t < 32) {
        const int b = t;
        const float plc = sm[SM_HD + b * 80 + 6] + sm[SM_HB + 6];
        out[OFF3 + (rb + b) * NC + c] = plc;           // output 3
        sm[SM_PSIG + b] = sigm(plc);
        float p[6], m[6];
#pragma unroll
        for (int i = 0; i < 6; ++i) p[i] = sm[SM_HD + b * 80 + i] + sm[SM_HB + i];
        geo(p, m);
#pragma unroll
        for (int i = 0; i < 6; ++i) sm[SM_M + b * 6 + i] = m[i];
    }
    __syncthreads();

    // D2c: pres_vote / scale_vote epilogues
#pragma unroll
    for (int p = 0; p < 10; ++p) {
        const int item = t + p * 256;
        const int b = item / 80, col = item % 80;
        if (col >= 7 && col < 79) {
            const float v = sm[SM_HD + b * 80 + col] + sm[SM_HB + col];
            const int base = ((rb + b) * NC + c) * NV;
            if (col < 43) {
                const int o = col - 7;
                out[OFF4 + base + o] = v;                                  // output 4
                out[OFF2 + base + o] = sm[SM_PSIG + b] * sigm(v);          // output 2
            } else {
                const int o = col - 43;
                float sp = v + 0.5f;
                sp = (sp > 15.0f) ? sp : log1pf(__expf(sp));
                out[OFF1 + base + o] = sp + 0.01f;                         // output 1
            }
        }
    }
    __syncthreads();

    // ============ Phase D4: cpr_dynamic = F @ Wdyn, 32x216, K=128 ============
    float l2loc = 0.0f;
    {
        const int txx = t & 31;   // cols txx*7..+6 (224 padded; guard >=216)
        const int tyy = t >> 5;   // rows tyy*4..+3
        float acc[4][7] = {};
        for (int k0 = 0; k0 < DH; k0 += 16) {
            __syncthreads();
#pragma unroll
            for (int p = 0; p < 14; ++p) {   // stage Wdyn chunk [16][216]
                const int idx = t + p * 256;
                if (idx < 3456)
                    sm[SM_WD + idx] = wdy[c * (DH * 216) + k0 * 216 + idx];
            }
            __syncthreads();
#pragma unroll 4
            for (int kk = 0; kk < 16; ++kk) {
                const float a0 = sm[SM_FST + (k0 + kk) * 33 + tyy * 4 + 0];
                const float a1 = sm[SM_FST + (k0 + kk) * 33 + tyy * 4 + 1];
                const float a2 = sm[SM_FST + (k0 + kk) * 33 + tyy * 4 + 2];
                const float a3 = sm[SM_FST + (k0 + kk) * 33 + tyy * 4 + 3];
#pragma unroll
                for (int j = 0; j < 7; ++j) {
                    const int cc = min(txx * 7 + j, 215);
                    const float w = sm[SM_WD + kk * 216 + cc];
                    acc[0][j] += a0 * w;
                    acc[1][j] += a1 * w;
                    acc[2][j] += a2 * w;
                    acc[3][j] += a3 * w;
                }
            }
        }
#pragma unroll
        for (int i = 0; i < 4; ++i)
#pragma unroll
            for (int j = 0; j < 7; ++j) {
                const int cc = txx * 7 + j;
                if (cc < 216)
                    sm[SM_DYN + (tyy * 4 + i) * 216 + cc] = acc[i][j];
            }
    }
    __syncthreads();

    // D4b: L2 sum + geometric transform + 3x3 vote matmul (output 0)
#pragma unroll
    for (int p = 0; p < 5; ++p) {
        const int item = t + p * 256;
        if (item < 32 * NV) {
            const int b = item / NV, v = item % NV;
            float dyn[6], pose[6], mB[6];
            float ss = 0.0f;
#pragma unroll
            for (int j = 0; j < 6; ++j) {
                dyn[j] = sm[SM_DYN + b * 216 + v * 6 + j];
                ss += dyn[j] * dyn[j];
                pose[j] = dyn[j] + cst[c * (NV * 6) + v * 6 + j];
            }
            l2loc += ss;
            geo(pose, mB);
            const float A0 = sm[SM_M + b * 6 + 0], A1 = sm[SM_M + b * 6 + 1];
            const float A2 = sm[SM_M + b * 6 + 2], A3 = sm[SM_M + b * 6 + 3];
            const float A4 = sm[SM_M + b * 6 + 4], A5 = sm[SM_M + b * 6 + 5];
            const int ob = (((rb + b) * NC + c) * NV + v) * 9;
            out[OFF0 + ob + 0] = A0 * mB[0] + A1 * mB[3];
            out[OFF0 + ob + 1] = A0 * mB[1] + A1 * mB[4];
            out[OFF0 + ob + 2] = A0 * mB[2] + A1 * mB[5] + A2;
            out[OFF0 + ob + 3] = A3 * mB[0] + A4 * mB[3];
            out[OFF0 + ob + 4] = A3 * mB[1] + A4 * mB[4];
            out[OFF0 + ob + 5] = A3 * mB[2] + A4 * mB[5] + A5;
            out[OFF0 + ob + 6] = 0.0f;
            out[OFF0 + ob + 7] = 0.0f;
            out[OFF0 + ob + 8] = 1.0f;
        }
    }

    // L2 scalar: wave reduce, one atomic per wave (output 5); /B/2 = /2048
    l2loc += __shfl_down(l2loc, 32, 64);
    l2loc += __shfl_down(l2loc, 16, 64);
    l2loc += __shfl_down(l2loc, 8, 64);
    l2loc += __shfl_down(l2loc, 4, 64);
    l2loc += __shfl_down(l2loc, 2, 64);
    l2loc += __shfl_down(l2loc, 1, 64);
    if ((t & 63) == 0) atomicAdd(&out[OFF5], l2loc * (1.0f / 2048.0f));
}

extern "C" void kernel_launch(void* const* d_in, const int* in_sizes, int n_in,
                              void* d_out, int out_size, void* d_ws, size_t ws_size,
                              hipStream_t stream)
{
    const float* feat = (const float*)d_in[0];
    const float* w1   = (const float*)d_in[1];
    const float* b1   = (const float*)d_in[2];
    const float* w2   = (const float*)d_in[3];
    const float* b2   = (const float*)d_in[4];
    const float* wm   = (const float*)d_in[5];
    const float* bm   = (const float*)d_in[6];
    const float* wdy  = (const float*)d_in[7];
    const float* wccr = (const float*)d_in[8];
    const float* bccr = (const float*)d_in[9];
    const float* wpc  = (const float*)d_in[10];
    const float* bpc  = (const float*)d_in[11];
    const float* wpv  = (const float*)d_in[12];
    const float* bpv  = (const float*)d_in[13];
    const float* wsv  = (const float*)d_in[14];
    const float* bsv  = (const float*)d_in[15];
    const float* cst  = (const float*)d_in[16];
    float* out = (float*)d_out;

    zero_l2_kernel<<<1, 1, 0, stream>>>(out);   // d_out is re-poisoned before every call
    dim3 grid(NB / 32, NC);
    caps_fused_kernel<<<grid, 256, 0, stream>>>(feat, w1, b1, w2, b2, wm, bm, wdy,
                                                wccr, bccr, wpc, bpc, wpv, bpv,
                                                wsv, bsv, cst, out);
}

// Round 2
// 622.319 us; speedup vs baseline: 1.0543x; 1.0543x over previous
//
#include <hip/hip_runtime.h>
#include <math.h>

// Problem constants
#define NB   1024
#define NC   64
#define DIN  256
#define DH   128
#define DCP  32
#define NV   36

// Output flat offsets (fp32 elements), reference return order.
#define OFF0 0
#define OFF1 21233664
#define OFF2 23592960
#define OFF3 25952256
#define OFF4 26017792
#define OFF5 28377088
#define OFF6 28377089
#define OFF7 30474241

// LDS layout (float indices). Three regions:
//  FST: persistent [128][33] activations (HsT then FsT)
//  R2 : phase-scratch union (max 4352 floats)
//  R3 : CPS [32][34] (B->C) unioned with M[32][6]+PSIG[32] (D2b->D4)
#define SM_FST 0
#define SM_R2  4224
#define SM_R3  8576
#define SM_TOT 9664        // 38656 bytes -> 4 blocks/CU (<=40960)

#define SM_XS  SM_R2           // A: [32][17]
#define SM_W1C (SM_R2 + 544)   // A: [16][128]
#define SM_W2S SM_R2           // B: [128][32]
#define SM_WM  SM_R2           // C: [33][128]
#define SM_WH  SM_R2           // D2: [16][80]
#define SM_HD  (SM_R2 + 1280)  // D2: [32][81]  (stride 81: kills 4-way write conflicts)
#define SM_HB  (SM_R2 + 3872)  // D2: [80]
#define SM_WD  SM_R2           // D4: [16][224] (216 cols padded to 224 for b128)
#define SM_DYN SM_R2           // D4: [32][109] half-buffer (reuses WD space)
#define SM_CPS SM_R3           // [32][34]
#define SM_M   SM_R3           // [32][6]   (CPS dead by then)
#define SM_PSIG (SM_R3 + 192)  // [32]

__device__ __forceinline__ float sigm(float x) { return 1.0f / (1.0f + __expf(-x)); }
__device__ __forceinline__ float tanh5(float x) {
    x = fminf(fmaxf(5.0f * x, -15.0f), 15.0f);
    float z = __expf(2.0f * x);
    return (z - 1.0f) / (z + 1.0f);
}
__device__ __forceinline__ void geo(const float* p, float* m) {
    float sx = sigm(p[0]) + 0.01f;
    float sy = sigm(p[1]) + 0.01f;
    float th = p[2] * 6.28318530717958647692f;
    float sh = tanh5(p[3]);
    float tx = tanh5(p[4]);
    float ty = tanh5(p[5]);
    float cc = __cosf(th), ss = __sinf(th);
    m[0] =  sx * cc + sh * sy * ss;
    m[1] = -sx * ss + sh * sy * cc;
    m[2] = tx;
    m[3] = sy * ss;
    m[4] = sy * cc;
    m[5] = ty;
}

__global__ void zero_l2_kernel(float* out) { out[OFF5] = 0.0f; }

__global__ __launch_bounds__(256, 4)   // 4 waves/EU -> 4 blocks/CU, VGPR<=128
void caps_fused_kernel(const float* __restrict__ feat,
                       const float* __restrict__ w1,  const float* __restrict__ b1,
                       const float* __restrict__ w2,  const float* __restrict__ b2,
                       const float* __restrict__ wm,  const float* __restrict__ bm,
                       const float* __restrict__ wdy,
                       const float* __restrict__ wccr,const float* __restrict__ bccr,
                       const float* __restrict__ wpc, const float* __restrict__ bpc,
                       const float* __restrict__ wpv, const float* __restrict__ bpv,
                       const float* __restrict__ wsv, const float* __restrict__ bsv,
                       const float* __restrict__ cst,
                       float* __restrict__ out)
{
    __shared__ float sm[SM_TOT];
    const int t  = threadIdx.x;
    const int c  = blockIdx.y;
    const int rb = blockIdx.x * 32;

    // ===== Phase A: HsT = relu(X @ W1 + b1)^T, 32x128, K=256, chunks of 16 =====
    {
        const int tx = t & 31;          // h-cols tx*4..+3
        const int ty = t >> 5;          // b-rows ty*4..+3
        float acc[4][4] = {};
        const int xrow = t >> 3, xk2 = (t & 7) * 2;
        for (int k0 = 0; k0 < DIN; k0 += 16) {
            __syncthreads();
            {   // stage X chunk [32][17 pad] + features passthrough (output 7)
                const int gi = (rb + xrow) * (NC * DIN) + c * DIN + k0 + xk2;
                const float2 v = *(const float2*)&feat[gi];
                sm[SM_XS + xrow * 17 + xk2]     = v.x;
                sm[SM_XS + xrow * 17 + xk2 + 1] = v.y;
                out[OFF7 + gi]     = v.x;      // OFF7 odd -> scalar stores
                out[OFF7 + gi + 1] = v.y;
            }
            // stage W1 chunk [16][128] contiguous: 2 float4/thread
            *(float4*)&sm[SM_W1C + t * 4] =
                *(const float4*)&w1[c * (DIN * DH) + k0 * DH + t * 4];
            *(float4*)&sm[SM_W1C + (t + 256) * 4] =
                *(const float4*)&w1[c * (DIN * DH) + k0 * DH + (t + 256) * 4];
            __syncthreads();
#pragma unroll
            for (int kk = 0; kk < 16; ++kk) {
                const float a0 = sm[SM_XS + (ty * 4 + 0) * 17 + kk];
                const float a1 = sm[SM_XS + (ty * 4 + 1) * 17 + kk];
                const float a2 = sm[SM_XS + (ty * 4 + 2) * 17 + kk];
                const float a3 = sm[SM_XS + (ty * 4 + 3) * 17 + kk];
                const float4 bv = *(const float4*)&sm[SM_W1C + kk * DH + tx * 4];
                acc[0][0] += a0 * bv.x; acc[0][1] += a0 * bv.y; acc[0][2] += a0 * bv.z; acc[0][3] += a0 * bv.w;
                acc[1][0] += a1 * bv.x; acc[1][1] += a1 * bv.y; acc[1][2] += a1 * bv.z; acc[1][3] += a1 * bv.w;
                acc[2][0] += a2 * bv.x; acc[2][1] += a2 * bv.y; acc[2][2] += a2 * bv.z; acc[2][3] += a2 * bv.w;
                acc[3][0] += a3 * bv.x; acc[3][1] += a3 * bv.y; acc[3][2] += a3 * bv.z; acc[3][3] += a3 * bv.w;
            }
        }
        const float4 bb4 = *(const float4*)&b1[c * DH + tx * 4];
        const float bb[4] = { bb4.x, bb4.y, bb4.z, bb4.w };
#pragma unroll
        for (int i = 0; i < 4; ++i)
#pragma unroll
            for (int j = 0; j < 4; ++j) {
                float v = fmaxf(acc[i][j] + bb[j], 0.0f);
                sm[SM_FST + (tx * 4 + j) * 33 + (ty * 4 + i)] = v;
            }
    }
    __syncthreads();

    // ===== Phase B: raw = relu(H @ W2 + b2), 32x32, K=128 =====
#pragma unroll
    for (int p = 0; p < 4; ++p) {
        const int idx = t + p * 256;
        *(float4*)&sm[SM_W2S + idx * 4] = *(const float4*)&w2[c * (DH * DCP) + idx * 4];
    }
    __syncthreads();
    {
        const int b  = t & 31;
        const int j4 = (t >> 5) << 2;
        float acc[4] = {};
#pragma unroll 8
        for (int k = 0; k < DH; ++k) {
            const float h = sm[SM_FST + k * 33 + b];
            const float4 wv = *(const float4*)&sm[SM_W2S + k * DCP + j4];
            acc[0] += h * wv.x; acc[1] += h * wv.y; acc[2] += h * wv.z; acc[3] += h * wv.w;
        }
#pragma unroll
        for (int jj = 0; jj < 4; ++jj) {
            const float v = fmaxf(acc[jj] + b2[c * DCP + j4 + jj], 0.0f);
            out[OFF6 + ((rb + b) * NC + c) * DCP + j4 + jj] = v;
            sm[SM_CPS + b * 34 + j4 + jj] = v;
        }
        if (t < 32) sm[SM_CPS + t * 34 + 32] = 1.0f;
    }
    __syncthreads();

    // ===== Phase C: caps_feat = relu(CP @ Wm + bm), 32x128, K=33 =====
#pragma unroll
    for (int p = 0; p < 5; ++p) {
        const int idx = t + p * 256;
        if (idx < 1056)
            *(float4*)&sm[SM_WM + idx * 4] = *(const float4*)&wm[c * (33 * DH) + idx * 4];
    }
    __syncthreads();
    {
        const int b  = t & 31;
        const int nb = (t >> 5) << 4;
        float acc[16] = {};
        for (int k = 0; k < 33; ++k) {
            const float a = sm[SM_CPS + b * 34 + k];
#pragma unroll
            for (int jq = 0; jq < 4; ++jq) {
                const float4 wv = *(const float4*)&sm[SM_WM + k * DH + nb + jq * 4];
                acc[jq*4+0] += a * wv.x; acc[jq*4+1] += a * wv.y;
                acc[jq*4+2] += a * wv.z; acc[jq*4+3] += a * wv.w;
            }
        }
#pragma unroll
        for (int j = 0; j < 16; ++j) {
            const float v = fmaxf(acc[j] + bm[c * DH + nb + j], 0.0f);
            sm[SM_FST + (nb + j) * 33 + b] = v;   // FsT overwrites HsT
        }
    }
    __syncthreads();

    // ===== Phase D2: heads [ccr|pres_caps|pres_vote|scale_vote], 32x80, K=128 =====
    {
        const int txx = t & 15;   // cols txx*5..+4
        const int tyy = t >> 4;   // rows tyy*2, tyy*2+1
        float acc[2][5] = {};
        for (int k0 = 0; k0 < DH; k0 += 16) {
            __syncthreads();
#pragma unroll
            for (int p = 0; p < 5; ++p) {   // stage [16][80] chunk
                const int idx = t + p * 256;
                const int kk = idx / 80, col = idx % 80;
                const int kg = k0 + kk;
                float v = 0.0f;
                if (col < 6)        v = wccr[c * (DH * 6) + kg * 6 + col];
                else if (col == 6)  v = wpc[c * DH + kg];
                else if (col < 43)  v = wpv[c * (DH * NV) + kg * NV + (col - 7)];
                else if (col < 79)  v = wsv[c * (DH * NV) + kg * NV + (col - 43)];
                sm[SM_WH + kk * 80 + col] = v;
            }
            if (k0 == 0 && t < 80) {   // stage biases once (after WM readers passed barrier)
                float v = 0.0f;
                if (t < 6)       v = bccr[c * 6 + t];
                else if (t == 6) v = bpc[c];
                else if (t < 43) v = bpv[c * NV + (t - 7)];
                else if (t < 79) v = bsv[c * NV + (t - 43)];
                sm[SM_HB + t] = v;
            }
            __syncthreads();
#pragma unroll
            for (int kk = 0; kk < 16; ++kk) {
                const float a0 = sm[SM_FST + (k0 + kk) * 33 + tyy * 2 + 0];
                const float a1 = sm[SM_FST + (k0 + kk) * 33 + tyy * 2 + 1];
#pragma unroll
                for (int j = 0; j < 5; ++j) {
                    const float w = sm[SM_WH + kk * 80 + txx * 5 + j];
                    acc[0][j] += a0 * w;
                    acc[1][j] += a1 * w;
                }
            }
        }
#pragma unroll
        for (int i = 0; i < 2; ++i)
#pragma unroll
            for (int j = 0; j < 5; ++j)
                sm[SM_HD + (tyy * 2 + i) * 81 + txx * 5 + j] = acc[i][j];
    }
    __syncthreads();

    // D2b: ccr matrices + pres_caps sigmoid
    if (t < 32) {
        const int b = t;
        const float plc = sm[SM_HD + b * 81 + 6] + sm[SM_HB + 6];
        out[OFF3 + (rb + b) * NC + c] = plc;
        sm[SM_PSIG + b] = sigm(plc);
        float p[6], m[6];
#pragma unroll
        for (int i = 0; i < 6; ++i) p[i] = sm[SM_HD + b * 81 + i] + sm[SM_HB + i];
        geo(p, m);
#pragma unroll
        for (int i = 0; i < 6; ++i) sm[SM_M + b * 6 + i] = m[i];
    }
    __syncthreads();

    // D2c: pres_vote / scale_vote epilogues
#pragma unroll
    for (int p = 0; p < 10; ++p) {
        const int item = t + p * 256;
        const int b = item / 80, col = item % 80;
        if (col >= 7 && col < 79) {
            const float v = sm[SM_HD + b * 81 + col] + sm[SM_HB + col];
            const int base = ((rb + b) * NC + c) * NV;
            if (col < 43) {
                const int o = col - 7;
                out[OFF4 + base + o] = v;
                out[OFF2 + base + o] = sm[SM_PSIG + b] * sigm(v);
            } else {
                const int o = col - 43;
                float sp = v + 0.5f;
                sp = (sp > 15.0f) ? sp : log1pf(__expf(sp));
                out[OFF1 + base + o] = sp + 0.01f;
            }
        }
    }

    // ===== Phase D4: cpr_dynamic = F @ Wdyn, 32x216(pad 224), K=128 =====
    float l2loc = 0.0f;
    {
        const int g   = t & 63;    // col group: cols 4g..4g+3 (g>=54 = padding)
        const int ty4 = t >> 6;    // rows ty4*8..+7
        float acc[8][4] = {};
        for (int k0 = 0; k0 < DH; k0 += 16) {
            __syncthreads();       // also protects HD reads (D2c) before WD overwrite
#pragma unroll
            for (int p = 0; p < 7; ++p) {   // stage [16][224] via float2
                const int i2  = t + p * 256;       // 0..1791
                const int col = (i2 * 2) % 224;
                const int row = (i2 * 2) / 224;
                float2 v = make_float2(0.0f, 0.0f);
                if (col < 216)
                    v = *(const float2*)&wdy[c * (DH * 216) + (k0 + row) * 216 + col];
                *(float2*)&sm[SM_WD + row * 224 + col] = v;
            }
            __syncthreads();
#pragma unroll
            for (int kk = 0; kk < 16; ++kk) {
                float a[8];
#pragma unroll
                for (int i = 0; i < 8; ++i)
                    a[i] = sm[SM_FST + (k0 + kk) * 33 + ty4 * 8 + i];
                const float4 w = *(const float4*)&sm[SM_WD + kk * 224 + g * 4];
#pragma unroll
                for (int i = 0; i < 8; ++i) {
                    acc[i][0] += a[i] * w.x; acc[i][1] += a[i] * w.y;
                    acc[i][2] += a[i] * w.z; acc[i][3] += a[i] * w.w;
                }
            }
        }
        // two halves of 108 cols: write DYN, then epilogue
        for (int half = 0; half < 2; ++half) {
            __syncthreads();   // prior WD/DYN readers done
            if (g < 54 && (g >= 27) == (half == 1)) {
#pragma unroll
                for (int i = 0; i < 8; ++i)
#pragma unroll
                    for (int j = 0; j < 4; ++j)
                        sm[SM_DYN + (ty4 * 8 + i) * 109 + (g * 4 + j - half * 108)] = acc[i][j];
            }
            __syncthreads();
#pragma unroll
            for (int p = 0; p < 3; ++p) {
                const int item = t + p * 256;
                if (item < 576) {
                    const int b = item / 18, vh = item % 18;
                    const int v = half * 18 + vh;
                    float dyn[6], pose[6], mB[6];
                    float ss = 0.0f;
#pragma unroll
                    for (int j = 0; j < 6; ++j) {
                        dyn[j] = sm[SM_DYN + b * 109 + vh * 6 + j];
                        ss += dyn[j] * dyn[j];
                        pose[j] = dyn[j] + cst[c * (NV * 6) + v * 6 + j];
                    }
                    l2loc += ss;
                    geo(pose, mB);
                    const float A0 = sm[SM_M + b * 6 + 0], A1 = sm[SM_M + b * 6 + 1];
                    const float A2 = sm[SM_M + b * 6 + 2], A3 = sm[SM_M + b * 6 + 3];
                    const float A4 = sm[SM_M + b * 6 + 4], A5 = sm[SM_M + b * 6 + 5];
                    const int ob = (((rb + b) * NC + c) * NV + v) * 9;
                    out[OFF0 + ob + 0] = A0 * mB[0] + A1 * mB[3];
                    out[OFF0 + ob + 1] = A0 * mB[1] + A1 * mB[4];
                    out[OFF0 + ob + 2] = A0 * mB[2] + A1 * mB[5] + A2;
                    out[OFF0 + ob + 3] = A3 * mB[0] + A4 * mB[3];
                    out[OFF0 + ob + 4] = A3 * mB[1] + A4 * mB[4];
                    out[OFF0 + ob + 5] = A3 * mB[2] + A4 * mB[5] + A5;
                    out[OFF0 + ob + 6] = 0.0f;
                    out[OFF0 + ob + 7] = 0.0f;
                    out[OFF0 + ob + 8] = 1.0f;
                }
            }
        }
    }

    // L2 scalar: wave reduce, one atomic per wave; /B/2 = /2048
    l2loc += __shfl_down(l2loc, 32, 64);
    l2loc += __shfl_down(l2loc, 16, 64);
    l2loc += __shfl_down(l2loc, 8, 64);
    l2loc += __shfl_down(l2loc, 4, 64);
    l2loc += __shfl_down(l2loc, 2, 64);
    l2loc += __shfl_down(l2loc, 1, 64);
    if ((t & 63) == 0) atomicAdd(&out[OFF5], l2loc * (1.0f / 2048.0f));
}

extern "C" void kernel_launch(void* const* d_in, const int* in_sizes, int n_in,
                              void* d_out, int out_size, void* d_ws, size_t ws_size,
                              hipStream_t stream)
{
    const float* feat = (const float*)d_in[0];
    const float* w1   = (const float*)d_in[1];
    const float* b1   = (const float*)d_in[2];
    const float* w2   = (const float*)d_in[3];
    const float* b2   = (const float*)d_in[4];
    const float* wm   = (const float*)d_in[5];
    const float* bm   = (const float*)d_in[6];
    const float* wdy  = (const float*)d_in[7];
    const float* wccr = (const float*)d_in[8];
    const float* bccr = (const float*)d_in[9];
    const float* wpc  = (const float*)d_in[10];
    const float* bpc  = (const float*)d_in[11];
    const float* wpv  = (const float*)d_in[12];
    const float* bpv  = (const float*)d_in[13];
    const float* wsv  = (const float*)d_in[14];
    const float* bsv  = (const float*)d_in[15];
    const float* cst  = (const float*)d_in[16];
    float* out = (float*)d_out;

    zero_l2_kernel<<<1, 1, 0, stream>>>(out);
    dim3 grid(NB / 32, NC);
    caps_fused_kernel<<<grid, 256, 0, stream>>>(feat, w1, b1, w2, b2, wm, bm, wdy,
                                                wccr, bccr, wpc, bpc, wpv, bpv,
                                                wsv, bsv, cst, out);
}